// Round 13
// baseline (373.390 us; speedup 1.0000x reference)
//
#include <hip/hip_runtime.h>

// ---------- types ----------
typedef __attribute__((ext_vector_type(8))) short  s8v;    // 8 bf16 (as shorts) = 4 VGPR
typedef __attribute__((ext_vector_type(8))) unsigned short us8;
typedef __attribute__((ext_vector_type(4))) unsigned short us4;
typedef __attribute__((ext_vector_type(4))) float  f4v;    // MFMA accumulator

// float -> bf16 round-to-nearest-even (inputs are finite)
__device__ __forceinline__ unsigned short f2bf(float f) {
  unsigned int u = __builtin_bit_cast(unsigned int, f);
  u += 0x7fffu + ((u >> 16) & 1u);
  return (unsigned short)(u >> 16);
}

// async global->LDS, 16B per lane; offset arg must stay 0 (only verified mode).
__device__ __forceinline__ void gll16(const void* g, void* l) {
  __builtin_amdgcn_global_load_lds(
      (const __attribute__((address_space(1))) unsigned int*)g,
      (__attribute__((address_space(3))) unsigned int*)l, 16, 0, 0);
}

// ---------- kernel 1: x fp32 -> bf16 ----------
__global__ __launch_bounds__(256) void cast_bf16(const float* __restrict__ in,
                                                 unsigned short* __restrict__ out) {
  const size_t i = (size_t)blockIdx.x * 256 + threadIdx.x;
  const f4v* p = (const f4v*)in;
  f4v a = p[2 * i];
  f4v b = p[2 * i + 1];
  us8 r;
  r[0] = f2bf(a[0]); r[1] = f2bf(a[1]); r[2] = f2bf(a[2]); r[3] = f2bf(a[3]);
  r[4] = f2bf(b[0]); r[5] = f2bf(b[1]); r[6] = f2bf(b[2]); r[7] = f2bf(b[3]);
  *(us8*)&out[i * 8] = r;
}

// ---------- kernel 2: T[(o1i1)*256+(o2i2)][r2] = sum_r1 c0*c1, bf16 out ----------
__global__ __launch_bounds__(256) void contract1b(const float* __restrict__ c0,
                                                  const float* __restrict__ c1,
                                                  unsigned short* __restrict__ T) {
  const int idx = blockIdx.x * 256 + threadIdx.x;   // 1,048,576
  const int r2q = idx & 15;
  const int oi2 = (idx >> 4) & 255;
  const int oi1 = idx >> 12;
  const float* c0p = c0 + oi1 * 64;
  const float* c1p = c1 + oi2 * 64 + r2q * 4;
  f4v s = (f4v)0.f;
#pragma unroll 8
  for (int r1 = 0; r1 < 64; ++r1) {
    const float t = c0p[r1];
    const f4v v = *(const f4v*)(c1p + r1 * 16384);
    s[0] = fmaf(t, v[0], s[0]); s[1] = fmaf(t, v[1], s[1]);
    s[2] = fmaf(t, v[2], s[2]); s[3] = fmaf(t, v[3], s[3]);
  }
  us4 o;
  o[0] = f2bf(s[0]); o[1] = f2bf(s[1]); o[2] = f2bf(s[2]); o[3] = f2bf(s[3]);
  *(us4*)&T[(size_t)idx * 4] = o;
}

// ---------- kernel 2b: c2t[n=o3*16+i3][k=r2] bf16 = c2[r2][n] ----------
__global__ __launch_bounds__(256) void transc2(const float* __restrict__ c2,
                                               unsigned short* __restrict__ c2t) {
  const int n = blockIdx.x * 16 + (threadIdx.x >> 4);
  const int j = threadIdx.x & 15;
  us4 o;
#pragma unroll
  for (int q = 0; q < 4; ++q) o[q] = f2bf(c2[(j * 4 + q) * 256 + n]);
  *(us4*)&c2t[(size_t)n * 64 + j * 4] = o;
}

// ---------- kernel 3: buildW3 — 256x256x64 MFMA mini-GEMM per (o1,o2) ----------
__global__ __launch_bounds__(256) void buildW3(const unsigned short* __restrict__ T,
                                               const unsigned short* __restrict__ c2t,
                                               unsigned short* __restrict__ W) {
  __shared__ unsigned short sT[16384];  // 32 KB [m 256][k 64] swizzled
  __shared__ unsigned short sC[16384];  // 32 KB [n 256][k 64] swizzled

  const int tid = threadIdx.x;
  const int o1 = blockIdx.x >> 4, o2 = blockIdx.x & 15;

#pragma unroll
  for (int j = 0; j < 8; ++j) {
    const int c = j * 256 + tid;
    const int m = c >> 3, sl = c & 7;
    const int dst = m * 64 + ((sl ^ (m & 7)) << 3);
    *(us8*)&sT[dst] = *(const us8*)(T + (size_t)(o1 * 16 + (m >> 4)) * 16384 +
                                    (o2 * 16 + (m & 15)) * 64 + sl * 8);
    *(us8*)&sC[dst] = *(const us8*)(c2t + (size_t)m * 64 + sl * 8);
  }
  __syncthreads();

  const int lane = tid & 63, wid = tid >> 6;
  const int fr = lane & 15, ks = lane >> 4;
  const int f7 = fr & 7;
  const int sx0 = ((ks ^ f7) << 3);
  const int sx1 = (((4 + ks) ^ f7) << 3);

  s8v a[4][2];
#pragma unroll
  for (int mi = 0; mi < 4; ++mi) {
    const unsigned short* p = &sT[(wid * 64 + mi * 16 + fr) * 64];
    a[mi][0] = *(const s8v*)(p + sx0);
    a[mi][1] = *(const s8v*)(p + sx1);
  }
#pragma unroll
  for (int nt = 0; nt < 16; ++nt) {
    const unsigned short* p = &sC[(nt * 16 + fr) * 64];
    const s8v b0 = *(const s8v*)(p + sx0);
    const s8v b1 = *(const s8v*)(p + sx1);
#pragma unroll
    for (int mi = 0; mi < 4; ++mi) {
      f4v acc = (f4v)0.f;
      acc = __builtin_amdgcn_mfma_f32_16x16x32_bf16(a[mi][0], b0, acc, 0, 0, 0);
      acc = __builtin_amdgcn_mfma_f32_16x16x32_bf16(a[mi][1], b1, acc, 0, 0, 0);
      unsigned short* wp = W + (size_t)(o1 * 256 + o2 * 16 + nt) * 4096 +
                           (wid * 4 + mi) * 256 + fr;
#pragma unroll
      for (int r = 0; r < 4; ++r) wp[(ks * 4 + r) * 16] = f2bf(acc[r]);
    }
  }
}

// ---------- kernel 4: 128x256-tile GEMM, BK=32, triple-buffered, 2 blocks/CU ----------
// A[M][K], B[N][K] bf16, C[M][N] fp32. M=8192, N=4096, K=4096.
// Mechanism change vs R9..R11 (all ~serial LDS+MFMA at 1 block/CU): 72 KiB LDS
// -> 2 co-resident blocks per CU with INDEPENDENT barrier domains; block A's
// LDS drain overlaps block B's MFMA in hardware (m114/m97 mechanism). Regs
// capped at 128 via __launch_bounds__(512,4) so 16 waves/CU fit.
// Per buf (12288 ushorts): A[128 rows][32] @0, B[256 rows][32] @4096.
// 64B rows; slot swizzle ^(row>>1)&3 on read, inverse on global source (R7-proven,
// 0 conflicts). Stage t+2 each iter (flight 2 iters ~1600cy); VMW(3)/iter.

#define BAR() __builtin_amdgcn_s_barrier()
#define VMW(N) asm volatile("s_waitcnt vmcnt(" #N ")" ::: "memory")

__global__ __launch_bounds__(512, 4) void gemmq(const unsigned short* __restrict__ A,
                                                const unsigned short* __restrict__ B,
                                                float* __restrict__ C) {
  constexpr int N = 4096, K = 4096;
  constexpr int NKT = K / 32;       // 128 K-tiles
  constexpr int NXT = N / 256;      // 16

  __shared__ unsigned short lds[36864];   // 72 KiB: 3 bufs x 12288

  const int tid  = threadIdx.x;
  const int lane = tid & 63;
  const int wid  = tid >> 6;
  const int wm   = wid >> 2;        // 0..1 -> M half (64 rows)
  const int wn   = wid & 3;         // 0..3 -> N quarter (64 cols)

  // XCD-aware bijective swizzle (gridDim.x = 1024, divisible by 8)
  const int cpx = (int)gridDim.x >> 3;
  const int wg  = ((int)blockIdx.x & 7) * cpx + ((int)blockIdx.x >> 3);
  const long bm = (long)(wg / NXT) * 128;
  const long bn = (long)(wg % NXT) * 256;

  // ---- staging addressing ----
  const int srow = tid >> 2;                       // 0..127
  const int scol = ((tid & 3) ^ ((srow >> 1) & 3)) * 8;   // inverse-swizzled slot
  const unsigned short* gA = A + (bm + srow) * (size_t)K + scol;
  const unsigned short* gB = B + (bn + srow) * (size_t)K + scol;
  const size_t b128off = 128 * (size_t)K;

  // stage one K-tile (A 8KB + B 16KB): 3 gll16/thread, linear LDS dests
#define STG(koff, bufU) do {                                        \
    gll16(gA + (koff),           &lds[(bufU) + tid * 8]);           \
    gll16(gB + (koff),           &lds[(bufU) + 4096 + tid * 8]);    \
    gll16(gB + b128off + (koff), &lds[(bufU) + 8192 + tid * 8]);    \
  } while (0)

  // ---- fragment read addressing (R7-proven pattern) ----
  const int fr = lane & 15;
  const int ks = lane >> 4;
  const int swz = (ks ^ ((fr >> 1) & 3)) * 8;
  const int aoff = (wm * 64 + fr) * 32 + swz;          // + mf*512
  const int boff = 4096 + (wn * 64 + fr) * 32 + swz;   // + nf*512

  f4v acc[4][4];
#pragma unroll
  for (int m = 0; m < 4; ++m)
#pragma unroll
    for (int n = 0; n < 4; ++n) acc[m][n] = (f4v)0.0f;

  // prologue: tile0 -> buf0, tile1 -> buf1
  STG(0, 0);
  STG(32, 12288);
  VMW(3);           // tile0 landed; tile1 flies
  BAR();

  int cu = 0, nx = 12288, s2 = 24576;   // reading buf, next buf, staging buf

  for (int t = 0; t < NKT; ++t) {
    const int koff = (t < NKT - 2) ? (t + 2) * 32 : 0;   // dummy wrap, in-bounds
    STG(koff, s2);
    VMW(3);         // t+1's 3 loads landed; t+2's fly
    BAR();

    s8v a[4], b[4];
#pragma unroll
    for (int mf = 0; mf < 4; ++mf) a[mf] = *(const s8v*)&lds[cu + aoff + mf * 512];
#pragma unroll
    for (int nf = 0; nf < 4; ++nf) b[nf] = *(const s8v*)&lds[cu + boff + nf * 512];

    __builtin_amdgcn_s_setprio(1);
#pragma unroll
    for (int mf = 0; mf < 4; ++mf)
#pragma unroll
      for (int nf = 0; nf < 4; ++nf)
        acc[mf][nf] = __builtin_amdgcn_mfma_f32_16x16x32_bf16(a[mf], b[nf], acc[mf][nf], 0, 0, 0);
    __builtin_amdgcn_s_setprio(0);
    BAR();

    const int tmp = s2; s2 = cu; cu = nx; nx = tmp;   // rotate buffers
  }
  VMW(0);           // drain dummy prefetches

  // ---- epilogue: C/D layout col = lane&15, row = (lane>>4)*4 + r ----
  const size_t crow0 = bm + wm * 64 + ks * 4;
  const size_t ccol0 = bn + wn * 64 + fr;
#pragma unroll
  for (int mf = 0; mf < 4; ++mf)
#pragma unroll
    for (int nf = 0; nf < 4; ++nf) {
      float* cp = C + (crow0 + mf * 16) * (size_t)N + ccol0 + nf * 16;
      f4v v = acc[mf][nf];
      cp[0] = v[0]; cp[N] = v[1]; cp[2 * (size_t)N] = v[2]; cp[3 * (size_t)N] = v[3];
    }
#undef STG
}

// ---------- launch ----------
extern "C" void kernel_launch(void* const* d_in, const int* in_sizes, int n_in,
                              void* d_out, int out_size, void* d_ws, size_t ws_size,
                              hipStream_t stream) {
  const float* x  = (const float*)d_in[0];   // [8192,4096]
  const float* c0 = (const float*)d_in[1];   // [1,16,16,64]
  const float* c1 = (const float*)d_in[2];   // [64,16,16,64]
  const float* c2 = (const float*)d_in[3];   // [64,16,16,1]
  float* out = (float*)d_out;                // [8192,4096] fp32

  char* ws = (char*)d_ws;
  unsigned short* T   = (unsigned short*)ws;                      // 8 MB  bf16
  unsigned short* c2t = (unsigned short*)(ws + (8u << 20));       // 32 KB bf16
  unsigned short* Wb  = (unsigned short*)(ws + (16u << 20));      // 32 MB bf16
  unsigned short* xb  = (unsigned short*)(ws + (48u << 20));      // 64 MB bf16

  hipLaunchKernelGGL(cast_bf16,  dim3(16384), dim3(256), 0, stream, x, xb);
  hipLaunchKernelGGL(contract1b, dim3(4096),  dim3(256), 0, stream, c0, c1, T);
  hipLaunchKernelGGL(transc2,    dim3(16),    dim3(256), 0, stream, c2, c2t);
  hipLaunchKernelGGL(buildW3,    dim3(256),   dim3(256), 0, stream, T, c2t, Wb);
  hipLaunchKernelGGL(gemmq,      dim3(1024),  dim3(512), 0, stream, xb, Wb, out);
}

// Round 14
// 306.940 us; speedup vs baseline: 1.2165x; 1.2165x over previous
//
#include <hip/hip_runtime.h>

// ---------- types ----------
typedef __attribute__((ext_vector_type(8))) short  s8v;    // 8 bf16 (as shorts) = 4 VGPR
typedef __attribute__((ext_vector_type(8))) unsigned short us8;
typedef __attribute__((ext_vector_type(4))) unsigned short us4;
typedef __attribute__((ext_vector_type(4))) float  f4v;    // MFMA accumulator

// float -> bf16 round-to-nearest-even (inputs are finite)
__device__ __forceinline__ unsigned short f2bf(float f) {
  unsigned int u = __builtin_bit_cast(unsigned int, f);
  u += 0x7fffu + ((u >> 16) & 1u);
  return (unsigned short)(u >> 16);
}

// async global->LDS, 16B per lane; offset arg must stay 0 (only verified mode).
__device__ __forceinline__ void gll16(const void* g, void* l) {
  __builtin_amdgcn_global_load_lds(
      (const __attribute__((address_space(1))) unsigned int*)g,
      (__attribute__((address_space(3))) unsigned int*)l, 16, 0, 0);
}

// ---------- kernel 1: x fp32 -> bf16 ----------
__global__ __launch_bounds__(256) void cast_bf16(const float* __restrict__ in,
                                                 unsigned short* __restrict__ out) {
  const size_t i = (size_t)blockIdx.x * 256 + threadIdx.x;
  const f4v* p = (const f4v*)in;
  f4v a = p[2 * i];
  f4v b = p[2 * i + 1];
  us8 r;
  r[0] = f2bf(a[0]); r[1] = f2bf(a[1]); r[2] = f2bf(a[2]); r[3] = f2bf(a[3]);
  r[4] = f2bf(b[0]); r[5] = f2bf(b[1]); r[6] = f2bf(b[2]); r[7] = f2bf(b[3]);
  *(us8*)&out[i * 8] = r;
}

// ---------- kernel 2: T[(o1i1)*256+(o2i2)][r2] = sum_r1 c0*c1, bf16 out ----------
__global__ __launch_bounds__(256) void contract1b(const float* __restrict__ c0,
                                                  const float* __restrict__ c1,
                                                  unsigned short* __restrict__ T) {
  const int idx = blockIdx.x * 256 + threadIdx.x;   // 1,048,576
  const int r2q = idx & 15;
  const int oi2 = (idx >> 4) & 255;
  const int oi1 = idx >> 12;
  const float* c0p = c0 + oi1 * 64;
  const float* c1p = c1 + oi2 * 64 + r2q * 4;
  f4v s = (f4v)0.f;
#pragma unroll 8
  for (int r1 = 0; r1 < 64; ++r1) {
    const float t = c0p[r1];
    const f4v v = *(const f4v*)(c1p + r1 * 16384);
    s[0] = fmaf(t, v[0], s[0]); s[1] = fmaf(t, v[1], s[1]);
    s[2] = fmaf(t, v[2], s[2]); s[3] = fmaf(t, v[3], s[3]);
  }
  us4 o;
  o[0] = f2bf(s[0]); o[1] = f2bf(s[1]); o[2] = f2bf(s[2]); o[3] = f2bf(s[3]);
  *(us4*)&T[(size_t)idx * 4] = o;
}

// ---------- kernel 2b: c2t[n=o3*16+i3][k=r2] bf16 = c2[r2][n] ----------
__global__ __launch_bounds__(256) void transc2(const float* __restrict__ c2,
                                               unsigned short* __restrict__ c2t) {
  const int n = blockIdx.x * 16 + (threadIdx.x >> 4);
  const int j = threadIdx.x & 15;
  us4 o;
#pragma unroll
  for (int q = 0; q < 4; ++q) o[q] = f2bf(c2[(j * 4 + q) * 256 + n]);
  *(us4*)&c2t[(size_t)n * 64 + j * 4] = o;
}

// ---------- kernel 3: buildW3 — 256x256x64 MFMA mini-GEMM per (o1,o2) ----------
__global__ __launch_bounds__(256) void buildW3(const unsigned short* __restrict__ T,
                                               const unsigned short* __restrict__ c2t,
                                               unsigned short* __restrict__ W) {
  __shared__ unsigned short sT[16384];  // 32 KB [m 256][k 64] swizzled
  __shared__ unsigned short sC[16384];  // 32 KB [n 256][k 64] swizzled

  const int tid = threadIdx.x;
  const int o1 = blockIdx.x >> 4, o2 = blockIdx.x & 15;

#pragma unroll
  for (int j = 0; j < 8; ++j) {
    const int c = j * 256 + tid;
    const int m = c >> 3, sl = c & 7;
    const int dst = m * 64 + ((sl ^ (m & 7)) << 3);
    *(us8*)&sT[dst] = *(const us8*)(T + (size_t)(o1 * 16 + (m >> 4)) * 16384 +
                                    (o2 * 16 + (m & 15)) * 64 + sl * 8);
    *(us8*)&sC[dst] = *(const us8*)(c2t + (size_t)m * 64 + sl * 8);
  }
  __syncthreads();

  const int lane = tid & 63, wid = tid >> 6;
  const int fr = lane & 15, ks = lane >> 4;
  const int f7 = fr & 7;
  const int sx0 = ((ks ^ f7) << 3);
  const int sx1 = (((4 + ks) ^ f7) << 3);

  s8v a[4][2];
#pragma unroll
  for (int mi = 0; mi < 4; ++mi) {
    const unsigned short* p = &sT[(wid * 64 + mi * 16 + fr) * 64];
    a[mi][0] = *(const s8v*)(p + sx0);
    a[mi][1] = *(const s8v*)(p + sx1);
  }
#pragma unroll
  for (int nt = 0; nt < 16; ++nt) {
    const unsigned short* p = &sC[(nt * 16 + fr) * 64];
    const s8v b0 = *(const s8v*)(p + sx0);
    const s8v b1 = *(const s8v*)(p + sx1);
#pragma unroll
    for (int mi = 0; mi < 4; ++mi) {
      f4v acc = (f4v)0.f;
      acc = __builtin_amdgcn_mfma_f32_16x16x32_bf16(a[mi][0], b0, acc, 0, 0, 0);
      acc = __builtin_amdgcn_mfma_f32_16x16x32_bf16(a[mi][1], b1, acc, 0, 0, 0);
      unsigned short* wp = W + (size_t)(o1 * 256 + o2 * 16 + nt) * 4096 +
                           (wid * 4 + mi) * 256 + fr;
#pragma unroll
      for (int r = 0; r < 4; ++r) wp[(ks * 4 + r) * 16] = f2bf(acc[r]);
    }
  }
}

// ---------- kernel 4: 256x256-tile 8-phase GEMM, cross-phase consumption ----------
// A[M][K], B[N][K] bf16, C[M][N] fp32. M=8192, N=4096, K=4096.
// buf0 = even K-tiles, buf1 = odd (fixed roles). Per buf: Alo@0,Ahi@8192,
// Blo@16384,Bhi@24576 (ushorts); buf1 = +32768. Swizzle as R7-R11 (0 conflicts).
// MFMA order per tile: (0,0)aLo*bL, (0,1)aLo*bH, (1,0)aHi*bL, (1,1)aHi*bH.
// Reads: P1-pre {aLo,bL,bH} (MFMA-P1 needs 12 of 16 -> counted lgkm); aHi read
// P2-post into the SAME bank as aLo (dead after P2) -> VGPR stays ~128.
// ONE barrier per phase + pub-barrier after VMW(2) at P4/P8 (10 bars/iter).
// Stage plan (each region's last consumer is >=2 phases before its stage; safe
// at 1-phase wave skew): P1:Blo(c1) P2:Ahi+Bhi(c1) P4:Alo(c0+2) P5:Blo(c0+2)
// P6:Ahi+Bhi(c0+2) P8:Alo(c1+2). VMW(2)@P4 lands all c1; VMW(2)@P8 all c0+2.

#define SBAR() do { asm volatile("" ::: "memory"); __builtin_amdgcn_s_barrier(); asm volatile("" ::: "memory"); } while (0)
#define VMW(N) asm volatile("s_waitcnt vmcnt(" #N ")" ::: "memory")

template<int MQ, int NQ>
__device__ __forceinline__ void mmq(f4v (&acc)[8][4], const s8v (&a)[4][2], const s8v (&b)[2][2]) {
  __builtin_amdgcn_s_setprio(1);
#pragma unroll
  for (int mi = 0; mi < 4; ++mi)
#pragma unroll
    for (int ni = 0; ni < 2; ++ni)
#pragma unroll
      for (int q = 0; q < 2; ++q)
        acc[MQ * 4 + mi][NQ * 2 + ni] = __builtin_amdgcn_mfma_f32_16x16x32_bf16(
            a[mi][q], b[ni][q], acc[MQ * 4 + mi][NQ * 2 + ni], 0, 0, 0);
  __builtin_amdgcn_s_setprio(0);
}

__global__ __launch_bounds__(512, 2) void gemm8(const unsigned short* __restrict__ A,
                                                const unsigned short* __restrict__ B,
                                                float* __restrict__ C) {
  constexpr int N = 4096, K = 4096;
  constexpr int NT = K / 64;
  constexpr int NITER = NT / 2;     // 32 iters, 2 K-tiles each
  constexpr int NXT = N / 256;

  __shared__ unsigned short lds[65536];   // 128 KiB

  const int tid  = threadIdx.x;
  const int lane = tid & 63;
  const int wid  = tid >> 6;
  const int wm   = wid >> 2;
  const int wn   = wid & 3;

  const int cpx = (int)gridDim.x >> 3;
  const int wg  = ((int)blockIdx.x & 7) * cpx + ((int)blockIdx.x >> 3);
  const long bm = (long)(wg / NXT) * 256;
  const long bn = (long)(wg % NXT) * 256;

  const int srow = tid >> 3;
  const int scol = ((tid & 7) ^ (srow & 7)) * 8;
  const unsigned short* gA = A + (bm + srow) * (size_t)K + scol;
  const unsigned short* gB = B + (bn + srow) * (size_t)K + scol;
  const size_t half64 = 64 * (size_t)K;
  const size_t k128   = 128 * (size_t)K;

#define STG(gp, koff, ldsU) do {                                  \
    const unsigned short* g_ = (gp) + (koff);                     \
    gll16(g_,          &lds[(ldsU) + tid * 8]);                   \
    gll16(g_ + half64, &lds[(ldsU) + 4096 + tid * 8]);            \
  } while (0)

  const int fr = lane & 15;
  const int ks = lane >> 4;
  const int f7 = fr & 7;
  const int sx0 = (ks ^ f7) * 8;
  const int sx1 = ((ks | 4) ^ f7) * 8;
  const int arow = (wm * 64 + fr) * 64;
  const int brow = (wn * 32 + fr) * 64;

#define RDA(MQ, bufU) do {                                                   \
    const unsigned short* p_ = &lds[(bufU) + (MQ) * 8192 + arow];            \
    a[0][0] = *(const s8v*)(p_ + sx0);        a[0][1] = *(const s8v*)(p_ + sx1); \
    a[1][0] = *(const s8v*)(p_ + 1024 + sx0); a[1][1] = *(const s8v*)(p_ + 1024 + sx1); \
    a[2][0] = *(const s8v*)(p_ + 2048 + sx0); a[2][1] = *(const s8v*)(p_ + 2048 + sx1); \
    a[3][0] = *(const s8v*)(p_ + 3072 + sx0); a[3][1] = *(const s8v*)(p_ + 3072 + sx1); \
  } while (0)
#define RDB(dst, NQ, bufU) do {                                              \
    const unsigned short* p_ = &lds[(bufU) + 16384 + (NQ) * 8192 + brow];    \
    dst[0][0] = *(const s8v*)(p_ + sx0);        dst[0][1] = *(const s8v*)(p_ + sx1); \
    dst[1][0] = *(const s8v*)(p_ + 1024 + sx0); dst[1][1] = *(const s8v*)(p_ + 1024 + sx1); \
  } while (0)

  f4v acc[8][4];
#pragma unroll
  for (int m = 0; m < 8; ++m)
#pragma unroll
    for (int n = 0; n < 4; ++n) acc[m][n] = (f4v)0.0f;

  // prologue: tile0 all 4 halves -> buf0; Alo(t1) -> buf1 (acts as "P8' stage")
  STG(gA,        0, 0);
  STG(gA + k128, 0, 8192);
  STG(gB,        0, 16384);
  STG(gB + k128, 0, 24576);
  STG(gA,        64, 32768);
  VMW(2);          // tile0's 8 loads drained; Alo(t1) flies
  SBAR();

  s8v a[4][2], bL[2][2], bH[2][2];

  for (int i = 0; i < NITER; ++i) {
    const long w46 = (i == NITER - 1) ? -128L : 0L;   // wrap dummy c0+2 stages
    const long w8  = (i == NITER - 1) ? -192L : 0L;   // wrap dummy c1+2 stage
    // ---- P1: pre {aLo,bL,bH}(c0); STG Blo(c1); MM(0,0) ----
    RDA(0, 0); RDB(bL, 0, 0); RDB(bH, 1, 0);
    STG(gB, 64, 32768 + 16384);
    SBAR(); mmq<0, 0>(acc, a, bL);
    // ---- P2: STG Ahi(c1)+Bhi(c1); MM(0,1); post-read aHi(c0) into a-bank ----
    STG(gA + k128, 64, 32768 + 8192);
    STG(gB + k128, 64, 32768 + 24576);
    SBAR(); mmq<0, 1>(acc, a, bH);
    RDA(1, 0);
    // ---- P3: MM(1,0) ----
    SBAR(); mmq<1, 0>(acc, a, bL);
    // ---- P4: STG Alo(c0+2); MM(1,1); VMW(2) lands ALL c1; pub ----
    STG(gA, 128 + w46, 0);
    SBAR(); mmq<1, 1>(acc, a, bH);
    VMW(2); SBAR();
    // ---- P5: pre {aLo,bL,bH}(c1); STG Blo(c0+2); MM(0,0) ----
    RDA(0, 32768); RDB(bL, 0, 32768); RDB(bH, 1, 32768);
    STG(gB, 128 + w46, 16384);
    SBAR(); mmq<0, 0>(acc, a, bL);
    // ---- P6: STG Ahi(c0+2)+Bhi(c0+2); MM(0,1); post-read aHi(c1) ----
    STG(gA + k128, 128 + w46, 8192);
    STG(gB + k128, 128 + w46, 24576);
    SBAR(); mmq<0, 1>(acc, a, bH);
    RDA(1, 32768);
    // ---- P7: MM(1,0) ----
    SBAR(); mmq<1, 0>(acc, a, bL);
    // ---- P8: STG Alo(c1+2); MM(1,1); VMW(2) lands ALL c0+2; pub ----
    STG(gA, 192 + w8, 32768);
    SBAR(); mmq<1, 1>(acc, a, bH);
    VMW(2); SBAR();

    gA += 128; gB += 128;
  }
  VMW(0);          // drain dummy prefetches

  // ---- epilogue: row = bm + mq*128 + wm*64 + mi*16 + ks*4 + r ; col = bn + nq*128 + wn*32 + ni*16 + fr
#pragma unroll
  for (int mq = 0; mq < 2; ++mq)
#pragma unroll
    for (int mi = 0; mi < 4; ++mi)
#pragma unroll
      for (int nq = 0; nq < 2; ++nq)
#pragma unroll
        for (int ni = 0; ni < 2; ++ni) {
          const size_t row0 = bm + mq * 128 + wm * 64 + mi * 16 + ks * 4;
          const size_t col  = bn + nq * 128 + wn * 32 + ni * 16 + fr;
          float* cp = C + row0 * (size_t)N + col;
          f4v v = acc[mq * 4 + mi][nq * 2 + ni];
          cp[0] = v[0]; cp[N] = v[1]; cp[2 * (size_t)N] = v[2]; cp[3 * (size_t)N] = v[3];
        }
#undef STG
#undef RDA
#undef RDB
}

// ---------- launch ----------
extern "C" void kernel_launch(void* const* d_in, const int* in_sizes, int n_in,
                              void* d_out, int out_size, void* d_ws, size_t ws_size,
                              hipStream_t stream) {
  const float* x  = (const float*)d_in[0];   // [8192,4096]
  const float* c0 = (const float*)d_in[1];   // [1,16,16,64]
  const float* c1 = (const float*)d_in[2];   // [64,16,16,64]
  const float* c2 = (const float*)d_in[3];   // [64,16,16,1]
  float* out = (float*)d_out;                // [8192,4096] fp32

  char* ws = (char*)d_ws;
  unsigned short* T   = (unsigned short*)ws;                      // 8 MB  bf16
  unsigned short* c2t = (unsigned short*)(ws + (8u << 20));       // 32 KB bf16
  unsigned short* Wb  = (unsigned short*)(ws + (16u << 20));      // 32 MB bf16
  unsigned short* xb  = (unsigned short*)(ws + (48u << 20));      // 64 MB bf16

  hipLaunchKernelGGL(cast_bf16,  dim3(16384), dim3(256), 0, stream, x, xb);
  hipLaunchKernelGGL(contract1b, dim3(4096),  dim3(256), 0, stream, c0, c1, T);
  hipLaunchKernelGGL(transc2,    dim3(16),    dim3(256), 0, stream, c2, c2t);
  hipLaunchKernelGGL(buildW3,    dim3(256),   dim3(256), 0, stream, T, c2t, Wb);
  hipLaunchKernelGGL(gemm8,      dim3(512),   dim3(512), 0, stream, xb, Wb, out);
}